// Round 4
// baseline (877.891 us; speedup 1.0000x reference)
//
#include <hip/hip_runtime.h>
#include <math.h>
#include <stdint.h>

#define NBMAX 512  // compile-time bound on bucket count (NB = ceil(N/256) = 391)

// ---------------- zero bucket counters ----------------
__global__ void k_zero(int* __restrict__ p, int n) {
    int i = blockIdx.x * 512 + threadIdx.x;
    if (i < n) p[i] = 0;
}

// ---------------- fused: coarse bucket histogram (LDS) + unscaled x@W1 ----------------
__global__ __launch_bounds__(256) void k_hist_gemm(
    const int* __restrict__ col, int* __restrict__ bucketCnt, int E, int hB, int NB,
    const float* __restrict__ x, const float* __restrict__ W1,
    float* __restrict__ xw, int n) {
    __shared__ float4 sW[2048];   // 32 KB (gemm branch)
    __shared__ int histL[NBMAX];  // hist branch
    if (blockIdx.x < hB) {
        for (int t = threadIdx.x; t < NB; t += 256) histL[t] = 0;
        __syncthreads();
        int base = blockIdx.x * 4096;
#pragma unroll
        for (int i = 0; i < 16; ++i) {
            int e = base + threadIdx.x + i * 256;
            if (e < E) atomicAdd(&histL[col[e] >> 8], 1);
        }
        __syncthreads();
        for (int t = threadIdx.x; t < NB; t += 256) {
            int c = histL[t];
            if (c) atomicAdd(&bucketCnt[t], c);
        }
        return;
    }
    const float4* w4 = (const float4*)W1;
    for (int p = threadIdx.x; p < 2048; p += 256) sW[p] = w4[p];
    __syncthreads();

    int idx  = (blockIdx.x - hB) * 256 + threadIdx.x;
    int node = idx >> 2, q = idx & 3;
    if (node >= n) return;

    const float4* xr = (const float4*)(x + (size_t)node * 512);
    float ax = 0.f, ay = 0.f, az = 0.f, aw = 0.f;
#pragma unroll 4
    for (int kk = 0; kk < 128; ++kk) {
        float4 xv  = xr[kk];
        float4 w0  = sW[(4 * kk + 0) * 4 + q];
        float4 w1v = sW[(4 * kk + 1) * 4 + q];
        float4 w2v = sW[(4 * kk + 2) * 4 + q];
        float4 w3v = sW[(4 * kk + 3) * 4 + q];
        ax = fmaf(xv.x, w0.x, ax);  ay = fmaf(xv.x, w0.y, ay);
        az = fmaf(xv.x, w0.z, az);  aw = fmaf(xv.x, w0.w, aw);
        ax = fmaf(xv.y, w1v.x, ax); ay = fmaf(xv.y, w1v.y, ay);
        az = fmaf(xv.y, w1v.z, az); aw = fmaf(xv.y, w1v.w, aw);
        ax = fmaf(xv.z, w2v.x, ax); ay = fmaf(xv.z, w2v.y, ay);
        az = fmaf(xv.z, w2v.z, az); aw = fmaf(xv.z, w2v.w, aw);
        ax = fmaf(xv.w, w3v.x, ax); ay = fmaf(xv.w, w3v.y, ay);
        az = fmaf(xv.w, w3v.z, az); aw = fmaf(xv.w, w3v.w, aw);
    }
    float4 r; r.x = ax; r.y = ay; r.z = az; r.w = aw;
    ((float4*)xw)[idx] = r;
}

// ---------------- scan bucket counts -> base, cursor ----------------
__global__ void k_scanB(const int* __restrict__ bucketCnt, int* __restrict__ baseB,
                        int* __restrict__ cursor, int NB, int E) {
    __shared__ int s[512];
    int t = threadIdx.x;
    int c = (t < NB) ? bucketCnt[t] : 0;
    s[t] = c;
    __syncthreads();
    for (int o = 1; o < 512; o <<= 1) {
        int v = (t >= o) ? s[t - o] : 0;
        __syncthreads();
        s[t] += v;
        __syncthreads();
    }
    if (t < NB) { int ex = s[t] - c; baseB[t] = ex; cursor[t] = ex; }
    if (t == NB) baseB[NB] = E;
}

// ---------------- bucket-scatter with LDS staging (coalesced flush) ----------------
__global__ __launch_bounds__(512) void k_bucket(
    const int* __restrict__ row, const int* __restrict__ col,
    int* __restrict__ cursor, unsigned int* __restrict__ sortedG, int E, int NB) {
    __shared__ int histL[NBMAX];
    __shared__ int offsL[NBMAX];
    __shared__ int gbL[NBMAX];
    __shared__ int sbuf[512];
    __shared__ unsigned int stageW[4096];
    __shared__ unsigned short stageB[4096];
    int t = threadIdx.x;
    for (int i = t; i < NB; i += 512) histL[i] = 0;
    __syncthreads();
    int off = blockIdx.x * 4096;
    unsigned int w[8]; int bk[8]; int rk[8];
#pragma unroll
    for (int i = 0; i < 8; ++i) {
        int e = off + t + i * 512;
        if (e < E) {
            int c = col[e], r = row[e];
            w[i]  = ((unsigned int)r << 8) | (unsigned int)(c & 255);
            bk[i] = c >> 8;
            rk[i] = atomicAdd(&histL[bk[i]], 1);
        } else bk[i] = -1;
    }
    __syncthreads();
    int cnt = (t < NB) ? histL[t] : 0;
    sbuf[t] = cnt;
    __syncthreads();
    for (int o = 1; o < 512; o <<= 1) {
        int v = (t >= o) ? sbuf[t - o] : 0;
        __syncthreads();
        sbuf[t] += v;
        __syncthreads();
    }
    if (t < NB) {
        offsL[t] = sbuf[t] - cnt;
        gbL[t]   = cnt ? atomicAdd(&cursor[t], cnt) : 0;
    }
    __syncthreads();
#pragma unroll
    for (int i = 0; i < 8; ++i) {
        if (bk[i] >= 0) {
            int s2 = offsL[bk[i]] + rk[i];
            stageW[s2] = w[i];
            stageB[s2] = (unsigned short)bk[i];
        }
    }
    __syncthreads();
    int total = min(4096, E - off);
    for (int s2 = t; s2 < total; s2 += 512) {
        int b = stageB[s2];
        sortedG[gbL[b] + (s2 - offsL[b])] = stageW[s2];
    }
}

// ---------------- per-bucket: degree from LDS histogram -> dinv + scale xw1 ----------------
__global__ __launch_bounds__(256) void k_deg_scale(
    const unsigned int* __restrict__ sortedG, const int* __restrict__ baseB,
    float* __restrict__ dinv, float* __restrict__ xw, int N) {
    __shared__ int dh[256];
    __shared__ float ds_[256];
    int t = threadIdx.x, b = blockIdx.x;
    dh[t] = 0;
    __syncthreads();
    int beg = baseB[b], end = baseB[b + 1];
    for (int i = beg + t; i < end; i += 256) atomicAdd(&dh[sortedG[i] & 255], 1);
    __syncthreads();
    int node = b * 256 + t;
    float dv = rsqrtf((float)(dh[t] + 1));  // +1 self-loop
    ds_[t] = dv;
    if (node < N) dinv[node] = dv;
    __syncthreads();
    float4* xw4 = (float4*)xw;
#pragma unroll
    for (int k = 0; k < 4; ++k) {
        int idx = t + k * 256;        // [0,1024) float4s of this bucket
        int nl  = idx >> 2;
        if (b * 256 + nl < N) {
            float4 v = xw4[(size_t)b * 1024 + idx];
            float s  = ds_[nl];
            v.x *= s; v.y *= s; v.z *= s; v.w *= s;
            xw4[(size_t)b * 1024 + idx] = v;
        }
    }
}

// ---------------- per-bucket layer-1 aggregate (LDS atomics) + fin1 epilogue ----------------
__global__ __launch_bounds__(1024) void k_agg1(
    const unsigned int* __restrict__ sortedG, const int* __restrict__ baseB,
    const float* __restrict__ sxw, const float* __restrict__ dinv,
    const float* __restrict__ W2, const float* __restrict__ b1,
    float* __restrict__ sxw2p, int N) {
    __shared__ float accL[4096];  // 256 nodes x 16
    __shared__ float sW2[112];
    __shared__ float sb1[16];
    int t = threadIdx.x, b = blockIdx.x;
    if (t < 112) sW2[t] = W2[t];
    if (t < 16)  sb1[t] = b1[t];
    for (int i = t; i < 4096; i += 1024) accL[i] = 0.f;
    __syncthreads();
    int beg = baseB[b], end = baseB[b + 1];
    const float4* s4 = (const float4*)sxw;
    int lane_e = t >> 2, q = t & 3;
    for (int eb = beg; eb < end; eb += 256) {
        int e = eb + lane_e;
        if (e < end) {
            unsigned int w = sortedG[e];
            int r = w >> 8, cl = w & 255;
            float4 v = s4[(size_t)r * 4 + q];
            int a = cl * 16 + q * 4;
            atomicAdd(&accL[a + 0], v.x);
            atomicAdd(&accL[a + 1], v.y);
            atomicAdd(&accL[a + 2], v.z);
            atomicAdd(&accL[a + 3], v.w);
        }
    }
    __syncthreads();
    if (t < 256) {
        int node = b * 256 + t;
        if (node < N) {
            float d = dinv[node];
            const float* selfp = sxw + (size_t)node * 16;
            float h[16];
#pragma unroll
            for (int j = 0; j < 16; ++j)
                h[j] = fmaxf(fmaf(d, accL[t * 16 + j] + selfp[j], sb1[j]), 0.f);
            float o[8] = {0, 0, 0, 0, 0, 0, 0, 0};
#pragma unroll
            for (int k = 0; k < 16; ++k) {
                float hk = h[k];
#pragma unroll
                for (int j = 0; j < 7; ++j) o[j] = fmaf(hk, sW2[k * 7 + j], o[j]);
            }
            float4 lo, hi;
            lo.x = o[0] * d; lo.y = o[1] * d; lo.z = o[2] * d; lo.w = o[3] * d;
            hi.x = o[4] * d; hi.y = o[5] * d; hi.z = o[6] * d; hi.w = 0.f;
            float4* dst = (float4*)(sxw2p + (size_t)node * 8);
            dst[0] = lo; dst[1] = hi;
        }
    }
}

// ---------------- per-bucket layer-2 aggregate + log_softmax epilogue ----------------
__global__ __launch_bounds__(1024) void k_agg2(
    const unsigned int* __restrict__ sortedG, const int* __restrict__ baseB,
    const float* __restrict__ sxw2p, const float* __restrict__ dinv,
    const float* __restrict__ b2, float* __restrict__ out, int N) {
    __shared__ float accL[2048];  // 256 nodes x 8 (padded)
    __shared__ float sb2[8];
    int t = threadIdx.x, b = blockIdx.x;
    if (t < 7) sb2[t] = b2[t];
    for (int i = t; i < 2048; i += 1024) accL[i] = 0.f;
    __syncthreads();
    int beg = baseB[b], end = baseB[b + 1];
    const float4* s4 = (const float4*)sxw2p;
    int lane_e = t >> 1, q = t & 1;
    for (int eb = beg; eb < end; eb += 512) {
        int e = eb + lane_e;
        if (e < end) {
            unsigned int w = sortedG[e];
            int r = w >> 8, cl = w & 255;
            float4 v = s4[(size_t)r * 2 + q];
            int a = cl * 8 + q * 4;
            atomicAdd(&accL[a + 0], v.x);
            atomicAdd(&accL[a + 1], v.y);
            atomicAdd(&accL[a + 2], v.z);
            atomicAdd(&accL[a + 3], v.w);   // pad column stays 0
        }
    }
    __syncthreads();
    if (t < 256) {
        int node = b * 256 + t;
        if (node < N) {
            float d = dinv[node];
            const float* selfp = sxw2p + (size_t)node * 8;
            float z[7];
            float m = -INFINITY;
#pragma unroll
            for (int j = 0; j < 7; ++j) {
                z[j] = fmaf(d, accL[t * 8 + j] + selfp[j], sb2[j]);
                m = fmaxf(m, z[j]);
            }
            float sum = 0.f;
#pragma unroll
            for (int j = 0; j < 7; ++j) sum += expf(z[j] - m);
            float l = m + logf(sum);
            size_t ob = (size_t)node * 7;
#pragma unroll
            for (int j = 0; j < 7; ++j) out[ob + j] = z[j] - l;
        }
    }
}

extern "C" void kernel_launch(void* const* d_in, const int* in_sizes, int n_in,
                              void* d_out, int out_size, void* d_ws, size_t ws_size,
                              hipStream_t stream) {
    const float* x  = (const float*)d_in[0];
    const int*   ei = (const int*)d_in[1];
    const float* W1 = (const float*)d_in[2];
    const float* b1 = (const float*)d_in[3];
    const float* W2 = (const float*)d_in[4];
    const float* b2 = (const float*)d_in[5];

    int N = in_sizes[0] / 512;  // 100000
    int E = in_sizes[1] / 2;    // 3200000
    const int* row = ei;        // sources
    const int* col = ei + E;    // targets

    int NB = (N + 255) >> 8;    // 391 buckets of 256 target nodes

    // workspace layout (int region then 16B-aligned float region)
    int* bucketCnt = (int*)d_ws;              // 512
    int* baseB     = bucketCnt + 512;         // 512 (NB+1 used)
    int* cursor    = baseB + 512;             // 512
    unsigned int* sortedG = (unsigned int*)(cursor + 512);  // E (E%4==0 keeps alignment)
    float* dinv  = (float*)(sortedG + E);     // N
    float* xw1   = dinv + N;                  // 16N (unscaled; scaled in place -> sxw1)
    float* sxw2p = xw1 + (size_t)16 * N;      // 8N (7 + zero pad)
    float* out   = (float*)d_out;

    int hB = (E + 4095) / 4096;          // 782 hist blocks
    int gG = (4 * N + 255) / 256;        // 1563 gemm blocks
    int bB = (E + 4095) / 4096;          // 782 bucket blocks

    k_zero     <<<1, 512, 0, stream>>>(bucketCnt, NB);
    k_hist_gemm<<<hB + gG, 256, 0, stream>>>(col, bucketCnt, E, hB, NB, x, W1, xw1, N);
    k_scanB    <<<1, 512, 0, stream>>>(bucketCnt, baseB, cursor, NB, E);
    k_bucket   <<<bB, 512, 0, stream>>>(row, col, cursor, sortedG, E, NB);
    k_deg_scale<<<NB, 256, 0, stream>>>(sortedG, baseB, dinv, xw1, N);
    k_agg1     <<<NB, 1024, 0, stream>>>(sortedG, baseB, xw1, dinv, W2, b1, sxw2p, N);
    k_agg2     <<<NB, 1024, 0, stream>>>(sortedG, baseB, sxw2p, dinv, b2, out, N);
}

// Round 5
// 458.067 us; speedup vs baseline: 1.9165x; 1.9165x over previous
//
#include <hip/hip_runtime.h>
#include <math.h>
#include <stdint.h>

#define NBMAX 512   // bucket-count bound (NB = ceil(N/256) = 391)
#define BCAP 10240  // per-bucket edge capacity (mean 8184, sigma ~90 -> 22 sigma margin)

// ---- bf16 helpers (OCP bf16 = upper 16 bits of fp32, RNE) ----
__device__ __forceinline__ unsigned int f2bf(float f) {
    unsigned int u = __float_as_uint(f);
    return (u + 0x7FFFu + ((u >> 16) & 1u)) >> 16;
}
__device__ __forceinline__ float bl(unsigned int u) { return __uint_as_float(u << 16); }
__device__ __forceinline__ float bh(unsigned int u) { return __uint_as_float(u & 0xFFFF0000u); }

// ---------------- zero bucket counters ----------------
__global__ void k_zero(int* __restrict__ p, int n) {
    int i = threadIdx.x;
    if (i < n) p[i] = 0;
}

// ---------------- fused: coarse bucket histogram (LDS) + unscaled x@W1 ----------------
__global__ __launch_bounds__(256) void k_hist_gemm(
    const int* __restrict__ col, int* __restrict__ bucketCnt, int E, int hB, int NB,
    const float* __restrict__ x, const float* __restrict__ W1,
    float* __restrict__ xw, int n) {
    __shared__ float4 sW[2048];
    __shared__ int histL[NBMAX];
    if (blockIdx.x < hB) {
        for (int t = threadIdx.x; t < NB; t += 256) histL[t] = 0;
        __syncthreads();
        int base = blockIdx.x * 4096;
#pragma unroll
        for (int i = 0; i < 16; ++i) {
            int e = base + threadIdx.x + i * 256;
            if (e < E) atomicAdd(&histL[col[e] >> 8], 1);
        }
        __syncthreads();
        for (int t = threadIdx.x; t < NB; t += 256) {
            int c = histL[t];
            if (c) atomicAdd(&bucketCnt[t], c);
        }
        return;
    }
    const float4* w4 = (const float4*)W1;
    for (int p = threadIdx.x; p < 2048; p += 256) sW[p] = w4[p];
    __syncthreads();

    int idx  = (blockIdx.x - hB) * 256 + threadIdx.x;
    int node = idx >> 2, q = idx & 3;
    if (node >= n) return;

    const float4* xr = (const float4*)(x + (size_t)node * 512);
    float ax = 0.f, ay = 0.f, az = 0.f, aw = 0.f;
#pragma unroll 4
    for (int kk = 0; kk < 128; ++kk) {
        float4 xv  = xr[kk];
        float4 w0  = sW[(4 * kk + 0) * 4 + q];
        float4 w1v = sW[(4 * kk + 1) * 4 + q];
        float4 w2v = sW[(4 * kk + 2) * 4 + q];
        float4 w3v = sW[(4 * kk + 3) * 4 + q];
        ax = fmaf(xv.x, w0.x, ax);  ay = fmaf(xv.x, w0.y, ay);
        az = fmaf(xv.x, w0.z, az);  aw = fmaf(xv.x, w0.w, aw);
        ax = fmaf(xv.y, w1v.x, ax); ay = fmaf(xv.y, w1v.y, ay);
        az = fmaf(xv.y, w1v.z, az); aw = fmaf(xv.y, w1v.w, aw);
        ax = fmaf(xv.z, w2v.x, ax); ay = fmaf(xv.z, w2v.y, ay);
        az = fmaf(xv.z, w2v.z, az); aw = fmaf(xv.z, w2v.w, aw);
        ax = fmaf(xv.w, w3v.x, ax); ay = fmaf(xv.w, w3v.y, ay);
        az = fmaf(xv.w, w3v.z, az); aw = fmaf(xv.w, w3v.w, aw);
    }
    float4 r; r.x = ax; r.y = ay; r.z = az; r.w = aw;
    ((float4*)xw)[idx] = r;
}

// ---------------- scan bucket counts -> base, cursor; offs[N]=E ----------------
__global__ void k_scanB(const int* __restrict__ bucketCnt, int* __restrict__ baseB,
                        int* __restrict__ cursor, int* __restrict__ offs,
                        int NB, int N, int E) {
    __shared__ int s[512];
    int t = threadIdx.x;
    int c = (t < NB) ? bucketCnt[t] : 0;
    s[t] = c;
    __syncthreads();
    for (int o = 1; o < 512; o <<= 1) {
        int v = (t >= o) ? s[t - o] : 0;
        __syncthreads();
        s[t] += v;
        __syncthreads();
    }
    if (t < NB) { int ex = s[t] - c; baseB[t] = ex; cursor[t] = ex; }
    if (t == NB) baseB[NB] = E;
    if (t == 0) offs[N] = E;
}

// ---------------- bucket-scatter with LDS staging (coalesced flush) ----------------
__global__ __launch_bounds__(512) void k_bucket(
    const int* __restrict__ row, const int* __restrict__ col,
    int* __restrict__ cursor, unsigned int* __restrict__ sortedG, int E, int NB) {
    __shared__ int histL[NBMAX];
    __shared__ int offsL[NBMAX];
    __shared__ int gbL[NBMAX];
    __shared__ int sbuf[512];
    __shared__ unsigned int stageW[4096];
    __shared__ unsigned short stageB[4096];
    int t = threadIdx.x;
    for (int i = t; i < NB; i += 512) histL[i] = 0;
    __syncthreads();
    int off = blockIdx.x * 4096;
    unsigned int w[8]; int bk[8]; int rk[8];
#pragma unroll
    for (int i = 0; i < 8; ++i) {
        int e = off + t + i * 512;
        if (e < E) {
            int c = col[e], r = row[e];
            w[i]  = ((unsigned int)r << 8) | (unsigned int)(c & 255);
            bk[i] = c >> 8;
            rk[i] = atomicAdd(&histL[bk[i]], 1);
        } else bk[i] = -1;
    }
    __syncthreads();
    int cnt = (t < NB) ? histL[t] : 0;
    sbuf[t] = cnt;
    __syncthreads();
    for (int o = 1; o < 512; o <<= 1) {
        int v = (t >= o) ? sbuf[t - o] : 0;
        __syncthreads();
        sbuf[t] += v;
        __syncthreads();
    }
    if (t < NB) {
        offsL[t] = sbuf[t] - cnt;
        gbL[t]   = cnt ? atomicAdd(&cursor[t], cnt) : 0;
    }
    __syncthreads();
#pragma unroll
    for (int i = 0; i < 8; ++i) {
        if (bk[i] >= 0) {
            int s2 = offsL[bk[i]] + rk[i];
            stageW[s2] = w[i];
            stageB[s2] = (unsigned short)bk[i];
        }
    }
    __syncthreads();
    int total = min(4096, E - off);
    for (int s2 = t; s2 < total; s2 += 512) {
        int b = stageB[s2];
        sortedG[gbL[b] + (s2 - offsL[b])] = stageW[s2];
    }
}

// ---------------- per-bucket: LDS counting sort (in place over sortedG),
//                  per-node offs, dinv, and scale+bf16 of xw1 ----------------
__global__ __launch_bounds__(512) void k_sortscale(
    unsigned int* __restrict__ sortedG, const int* __restrict__ baseB,
    int* __restrict__ offs, float* __restrict__ dinv,
    const float* __restrict__ xw, unsigned int* __restrict__ sxwh, int N) {
    __shared__ unsigned int wv[BCAP];
    __shared__ int hist[256];
    __shared__ int off_[256];
    __shared__ int sc[256];
    __shared__ float ds[256];
    int t = threadIdx.x, b = blockIdx.x;
    if (t < 256) hist[t] = 0;
    __syncthreads();
    int beg = baseB[b], end = baseB[b + 1];
    int cnt = end - beg;
    for (int i = t; i < cnt; i += 512) {
        unsigned int w = sortedG[beg + i];
        wv[i] = w;
        atomicAdd(&hist[w & 255], 1);
    }
    __syncthreads();
    if (t < 256) sc[t] = hist[t];
    __syncthreads();
    for (int o = 1; o < 256; o <<= 1) {
        int v = 0;
        if (t < 256 && t >= o) v = sc[t - o];
        __syncthreads();
        if (t < 256) sc[t] += v;
        __syncthreads();
    }
    if (t < 256) {
        off_[t] = sc[t] - hist[t];
        int node = b * 256 + t;
        float dv = rsqrtf((float)(hist[t] + 1));  // +1 self-loop
        ds[t] = dv;
        if (node < N) { offs[node] = beg + off_[t]; dinv[node] = dv; }
        hist[t] = 0;  // reuse as pass-2 rank cursor
    }
    __syncthreads();
    // place: node-sorted source rows written back over sortedG (reads done via wv)
    for (int i = t; i < cnt; i += 512) {
        unsigned int w = wv[i];
        int c = w & 255;
        int r2 = atomicAdd(&hist[c], 1);
        sortedG[beg + off_[c] + r2] = w >> 8;
    }
    // scale xw1 by dinv and convert to bf16 (bucket's node slab is contiguous)
    const float4* xw4 = (const float4*)xw;
    uint2* dsth = (uint2*)sxwh;
#pragma unroll
    for (int k = 0; k < 2; ++k) {
        int idx = t + k * 512;      // float4 index within 1024-float4 slab
        int nl  = idx >> 2;
        int node = b * 256 + nl;
        if (node < N) {
            float s = ds[nl];
            float4 v = xw4[(size_t)b * 1024 + idx];
            unsigned int u0 = f2bf(v.x * s), u1 = f2bf(v.y * s);
            unsigned int u2 = f2bf(v.z * s), u3 = f2bf(v.w * s);
            uint2 o; o.x = u0 | (u1 << 16); o.y = u2 | (u3 << 16);
            dsth[(size_t)b * 1024 + idx] = o;
        }
    }
}

// ---------------- layer-1 pull-gather (bf16 table) + fused fin1 epilogue ----------------
// 2 lanes per node; each lane owns 8 features (one uint4 = 8 bf16).
__global__ __launch_bounds__(256) void k_gather1f(
    const int* __restrict__ offs, const int* __restrict__ srow,
    const uint4* __restrict__ s4, const float* __restrict__ dinv,
    const float* __restrict__ W2, const float* __restrict__ b1,
    float* __restrict__ sxw2p, int N) {
    __shared__ float sW2[112];
    __shared__ float sb1[16];
    if (threadIdx.x < 112) sW2[threadIdx.x] = W2[threadIdx.x];
    if (threadIdx.x < 16) sb1[threadIdx.x] = b1[threadIdx.x];
    __syncthreads();
    int idx = blockIdx.x * 256 + threadIdx.x;
    int node = idx >> 1, q = idx & 1;
    if (node >= N) return;
    int beg = offs[node], end = offs[node + 1];

    uint4 sv = s4[(size_t)node * 2 + q];  // self-loop
    float a0 = bl(sv.x), a1 = bh(sv.x), a2 = bl(sv.y), a3 = bh(sv.y);
    float a4 = bl(sv.z), a5 = bh(sv.z), a6 = bl(sv.w), a7 = bh(sv.w);
    int j = beg;
    for (; j + 3 < end; j += 4) {
        int r0 = srow[j], r1 = srow[j + 1], r2 = srow[j + 2], r3 = srow[j + 3];
        uint4 v0 = s4[(size_t)r0 * 2 + q];
        uint4 v1 = s4[(size_t)r1 * 2 + q];
        uint4 v2 = s4[(size_t)r2 * 2 + q];
        uint4 v3 = s4[(size_t)r3 * 2 + q];
        a0 += (bl(v0.x) + bl(v1.x)) + (bl(v2.x) + bl(v3.x));
        a1 += (bh(v0.x) + bh(v1.x)) + (bh(v2.x) + bh(v3.x));
        a2 += (bl(v0.y) + bl(v1.y)) + (bl(v2.y) + bl(v3.y));
        a3 += (bh(v0.y) + bh(v1.y)) + (bh(v2.y) + bh(v3.y));
        a4 += (bl(v0.z) + bl(v1.z)) + (bl(v2.z) + bl(v3.z));
        a5 += (bh(v0.z) + bh(v1.z)) + (bh(v2.z) + bh(v3.z));
        a6 += (bl(v0.w) + bl(v1.w)) + (bl(v2.w) + bl(v3.w));
        a7 += (bh(v0.w) + bh(v1.w)) + (bh(v2.w) + bh(v3.w));
    }
    for (; j < end; ++j) {
        int r = srow[j];
        uint4 v = s4[(size_t)r * 2 + q];
        a0 += bl(v.x); a1 += bh(v.x); a2 += bl(v.y); a3 += bh(v.y);
        a4 += bl(v.z); a5 += bh(v.z); a6 += bl(v.w); a7 += bh(v.w);
    }
    // fin1: h = relu(d*a + b1); o = h @ W2 (pair-split rows, shfl-combine); sxw2p = d*o
    float d = dinv[node];
    float h[8];
    h[0] = fmaxf(fmaf(d, a0, sb1[q * 8 + 0]), 0.f);
    h[1] = fmaxf(fmaf(d, a1, sb1[q * 8 + 1]), 0.f);
    h[2] = fmaxf(fmaf(d, a2, sb1[q * 8 + 2]), 0.f);
    h[3] = fmaxf(fmaf(d, a3, sb1[q * 8 + 3]), 0.f);
    h[4] = fmaxf(fmaf(d, a4, sb1[q * 8 + 4]), 0.f);
    h[5] = fmaxf(fmaf(d, a5, sb1[q * 8 + 5]), 0.f);
    h[6] = fmaxf(fmaf(d, a6, sb1[q * 8 + 6]), 0.f);
    h[7] = fmaxf(fmaf(d, a7, sb1[q * 8 + 7]), 0.f);
    float o[7] = {0.f, 0.f, 0.f, 0.f, 0.f, 0.f, 0.f};
    int rbase = q * 8;
#pragma unroll
    for (int i = 0; i < 8; ++i) {
        float hv = h[i];
#pragma unroll
        for (int jj = 0; jj < 7; ++jj) o[jj] = fmaf(hv, sW2[(rbase + i) * 7 + jj], o[jj]);
    }
#pragma unroll
    for (int jj = 0; jj < 7; ++jj) o[jj] += __shfl_xor(o[jj], 1, 64);
    float4 wv4;
    if (q == 0) { wv4.x = o[0] * d; wv4.y = o[1] * d; wv4.z = o[2] * d; wv4.w = o[3] * d; }
    else        { wv4.x = o[4] * d; wv4.y = o[5] * d; wv4.z = o[6] * d; wv4.w = 0.f; }
    ((float4*)sxw2p)[(size_t)node * 2 + q] = wv4;
}

// ---------------- layer-2 pull-gather (fp32 padded table) + fused log_softmax ----------------
__global__ __launch_bounds__(256) void k_gather2f(
    const int* __restrict__ offs, const int* __restrict__ srow,
    const float* __restrict__ sxw2p, const float* __restrict__ dinv,
    const float* __restrict__ b2, float* __restrict__ out, int N) {
    __shared__ float sb2[8];
    if (threadIdx.x < 7) sb2[threadIdx.x] = b2[threadIdx.x];
    if (threadIdx.x == 7) sb2[7] = 0.f;
    __syncthreads();
    int idx = blockIdx.x * 256 + threadIdx.x;
    int node = idx >> 1, q = idx & 1;
    if (node >= N) return;
    int beg = offs[node], end = offs[node + 1];
    const float4* s4 = (const float4*)sxw2p;
    float4 a = s4[(size_t)node * 2 + q];  // self-loop
    int j = beg;
    for (; j + 3 < end; j += 4) {
        int r0 = srow[j], r1 = srow[j + 1], r2 = srow[j + 2], r3 = srow[j + 3];
        float4 v0 = s4[(size_t)r0 * 2 + q];
        float4 v1 = s4[(size_t)r1 * 2 + q];
        float4 v2 = s4[(size_t)r2 * 2 + q];
        float4 v3 = s4[(size_t)r3 * 2 + q];
        a.x += (v0.x + v1.x) + (v2.x + v3.x);
        a.y += (v0.y + v1.y) + (v2.y + v3.y);
        a.z += (v0.z + v1.z) + (v2.z + v3.z);
        a.w += (v0.w + v1.w) + (v2.w + v3.w);
    }
    for (; j < end; ++j) {
        int r = srow[j];
        float4 v = s4[(size_t)r * 2 + q];
        a.x += v.x; a.y += v.y; a.z += v.z; a.w += v.w;
    }
    float d = dinv[node];
    float z0 = fmaf(d, a.x, sb2[q * 4 + 0]);
    float z1 = fmaf(d, a.y, sb2[q * 4 + 1]);
    float z2 = fmaf(d, a.z, sb2[q * 4 + 2]);
    float z3 = (q == 0) ? fmaf(d, a.w, sb2[3]) : -INFINITY;
    float m = fmaxf(fmaxf(z0, z1), fmaxf(z2, z3));
    m = fmaxf(m, __shfl_xor(m, 1, 64));
    float s = expf(z0 - m) + expf(z1 - m) + expf(z2 - m) + ((q == 0) ? expf(z3 - m) : 0.f);
    s += __shfl_xor(s, 1, 64);
    float l = m + logf(s);
    float* ob = out + (size_t)node * 7;
    if (q == 0) { ob[0] = z0 - l; ob[1] = z1 - l; ob[2] = z2 - l; ob[3] = z3 - l; }
    else        { ob[4] = z0 - l; ob[5] = z1 - l; ob[6] = z2 - l; }
}

extern "C" void kernel_launch(void* const* d_in, const int* in_sizes, int n_in,
                              void* d_out, int out_size, void* d_ws, size_t ws_size,
                              hipStream_t stream) {
    const float* x  = (const float*)d_in[0];
    const int*   ei = (const int*)d_in[1];
    const float* W1 = (const float*)d_in[2];
    const float* b1 = (const float*)d_in[3];
    const float* W2 = (const float*)d_in[4];
    const float* b2 = (const float*)d_in[5];

    int N = in_sizes[0] / 512;  // 100000
    int E = in_sizes[1] / 2;    // 3200000
    const int* row = ei;        // sources
    const int* col = ei + E;    // targets

    int NB = (N + 255) >> 8;    // 391 buckets of 256 target nodes

    // workspace layout
    int* bucketCnt = (int*)d_ws;                      // 512
    int* baseB     = bucketCnt + 512;                 // 512 (NB+1 used)
    int* cursor    = baseB + 512;                     // 512
    int* offs      = cursor + 512;                    // N+1 (+pad to keep 16B align)
    unsigned int* sortedG = (unsigned int*)(offs + ((N + 4) & ~3));  // E (rows after sortscale)
    float* dinv  = (float*)(sortedG + E);             // N
    float* xw1   = dinv + N;                          // 16N fp32 (unscaled x@W1)
    unsigned int* sxwh = (unsigned int*)(xw1 + (size_t)16 * N);  // 8N uints = [N,16] bf16
    float* sxw2p = xw1;                               // 8N, aliases dead xw1
    float* out   = (float*)d_out;

    int hB = (E + 4095) / 4096;          // 782 hist blocks
    int gG = (4 * N + 255) / 256;        // 1563 gemm blocks
    int bB = (E + 4095) / 4096;          // 782 bucket blocks
    int gP = (2 * N + 255) / 256;        // 782 gather blocks

    k_zero     <<<1, 512, 0, stream>>>(bucketCnt, NB);
    k_hist_gemm<<<hB + gG, 256, 0, stream>>>(col, bucketCnt, E, hB, NB, x, W1, xw1, N);
    k_scanB    <<<1, 512, 0, stream>>>(bucketCnt, baseB, cursor, offs, NB, N, E);
    k_bucket   <<<bB, 512, 0, stream>>>(row, col, cursor, sortedG, E, NB);
    k_sortscale<<<NB, 512, 0, stream>>>(sortedG, baseB, offs, dinv, xw1, sxwh, N);
    k_gather1f <<<gP, 256, 0, stream>>>(offs, (const int*)sortedG, (const uint4*)sxwh,
                                        dinv, W2, b1, sxw2p, N);
    k_gather2f <<<gP, 256, 0, stream>>>(offs, (const int*)sortedG, sxw2p, dinv, b2, out, N);
}